// Round 1
// baseline (1149.799 us; speedup 1.0000x reference)
//
#include <hip/hip_runtime.h>
#include <hip/hip_bf16.h>
#include <math.h>

#define NPAD 16384
#define NRES 8192
#define NIN  4096

// Exact bf16->fp32 (bit shift); bf==false reads fp32 directly.
__device__ __forceinline__ float ldval(const void* p, int idx, bool bf) {
    if (bf) {
        unsigned int u = ((const unsigned short*)p)[idx];
        return __uint_as_float(u << 16);
    }
    return ((const float*)p)[idx];
}

// H_16 butterflies over the register index (4 stages, in-register).
__device__ __forceinline__ void reg_h16(float a[16]) {
#pragma unroll
    for (int m = 1; m < 16; m <<= 1) {
#pragma unroll
        for (int j = 0; j < 16; ++j) {
            if ((j & m) == 0) {
                float u = a[j], v = a[j | m];
                a[j]     = u + v;
                a[j | m] = u - v;
            }
        }
    }
}

// H_64 butterflies over the lane index (6 stages, shfl_xor, no barriers).
__device__ __forceinline__ void lane_h64(float a[16], int l) {
#pragma unroll
    for (int m = 1; m < 64; m <<= 1) {
#pragma unroll
        for (int j = 0; j < 16; ++j) {
            float p = __shfl_xor(a[j], m, 64);
            a[j] = (l & m) ? (p - a[j]) : (a[j] + p);
        }
    }
}

// One workgroup does the whole problem: 16384 = 16(reg) x 16(wave) x 64(lane).
// Layout A: thread t holds a[j] = X[j*1024 + t]           (reg dim = bits 10..13)
// Layout B: thread t holds a[j] = X[(t>>6)*1024 + j*64 + (t&63)]  (reg dim = bits 6..9)
// Each layer: D-signflip, reg H16, lane H64, LDS transpose (A<->B), reg H16.
__global__ void __launch_bounds__(1024)
structured_transform_kernel(const void* __restrict__ state,
                            const void* __restrict__ inp,
                            const void* __restrict__ Dm,
                            const void* __restrict__ H,
                            const void* __restrict__ bias,
                            void* __restrict__ out)
{
    __shared__ float lds[NPAD];  // 64 KB
    const int t = threadIdx.x;
    const int w = t >> 6;
    const int l = t & 63;

    // Runtime dtype detection: H[0][0] == +1.0. fp32 -> 0x3F800000,
    // packed bf16 (H[0],H[1] = +1,+1) -> 0x3F803F80.
    const bool bf = (((const unsigned int*)H)[0] != 0x3F800000u);

    float a[16];

    // Initial load, layout A: X = [0.9*state(8192), 0.4*inputs(4096), 0(4096)]
#pragma unroll
    for (int j = 0; j < 16; ++j) {
        int idx = j * 1024 + t;
        float v;
        if (idx < NRES)            v = 0.9f * ldval(state, idx, bf);
        else if (idx < NRES + NIN) v = 0.4f * ldval(inp, idx - NRES, bf);
        else                       v = 0.0f;
        a[j] = v;
    }

    // ---- Layer 0 (enters layout A, exits layout B) ----
#pragma unroll
    for (int j = 0; j < 16; ++j) a[j] *= ldval(Dm, 0 * NPAD + j * 1024 + t, bf);
    reg_h16(a);       // bits 10..13
    lane_h64(a, l);   // bits 0..5
#pragma unroll
    for (int j = 0; j < 16; ++j) lds[j * 1024 + t] = a[j];
    __syncthreads();
#pragma unroll
    for (int j = 0; j < 16; ++j) a[j] = lds[w * 1024 + j * 64 + l];
    reg_h16(a);       // bits 6..9

    // ---- Layer 1 (enters layout B, exits layout A) ----
#pragma unroll
    for (int j = 0; j < 16; ++j) a[j] *= ldval(Dm, 1 * NPAD + w * 1024 + j * 64 + l, bf);
    reg_h16(a);       // bits 6..9
    lane_h64(a, l);   // bits 0..5
    __syncthreads();  // WAR: everyone done reading LDS from layer 0
#pragma unroll
    for (int j = 0; j < 16; ++j) lds[w * 1024 + j * 64 + l] = a[j];
    __syncthreads();
#pragma unroll
    for (int j = 0; j < 16; ++j) a[j] = lds[j * 1024 + t];
    reg_h16(a);       // bits 10..13

    // ---- Layer 2 (enters layout A, exits layout B) ----
#pragma unroll
    for (int j = 0; j < 16; ++j) a[j] *= ldval(Dm, 2 * NPAD + j * 1024 + t, bf);
    reg_h16(a);       // bits 10..13
    lane_h64(a, l);   // bits 0..5
    __syncthreads();  // WAR
#pragma unroll
    for (int j = 0; j < 16; ++j) lds[j * 1024 + t] = a[j];
    __syncthreads();
#pragma unroll
    for (int j = 0; j < 16; ++j) a[j] = lds[w * 1024 + j * 64 + l];
    reg_h16(a);       // bits 6..9

    // Epilogue (layout B): element idx = w*1024 + j*64 + l; idx < 8192 <=> w < 8.
    // out = erf(X[:8192]/16384 + bias)   (LEAK = 1.0 kills the state term)
    if (w < 8) {
        const float inv = 1.0f / 16384.0f;
#pragma unroll
        for (int j = 0; j < 16; ++j) {
            int idx = w * 1024 + j * 64 + l;
            float x = a[j] * inv + ldval(bias, idx, bf);
            float r = erff(x);
            if (bf) ((__hip_bfloat16*)out)[idx] = __float2bfloat16(r);
            else    ((float*)out)[idx] = r;
        }
    }
}

extern "C" void kernel_launch(void* const* d_in, const int* in_sizes, int n_in,
                              void* d_out, int out_size, void* d_ws, size_t ws_size,
                              hipStream_t stream) {
    // inputs: 0=state(8192), 1=inputs(4096), 2=D(3*16384), 3=H(16384^2, unused
    // except for dtype sniffing), 4=bias(8192)
    structured_transform_kernel<<<1, 1024, 0, stream>>>(
        d_in[0], d_in[1], d_in[2], d_in[3], d_in[4], d_out);
}